// Round 7
// baseline (263.801 us; speedup 1.0000x reference)
//
#include <hip/hip_runtime.h>
#include <hip/hip_bf16.h>
#include <stdint.h>

// OuterProductMean: B=1, S=512, R=256, C_M=256, C_P=32, C_Z=128
#define S_DIM 512
#define R_DIM 256
#define CM 256
#define CP 32
#define CZ 128

typedef __attribute__((ext_vector_type(8))) short bf16x8;
typedef __attribute__((ext_vector_type(4))) float f32x4;
typedef __attribute__((ext_vector_type(16))) float f32x16;
typedef unsigned int u32;

__device__ __forceinline__ float bf2f(unsigned short u) {
  union { u32 i; float f; } v; v.i = ((u32)u) << 16; return v.f;
}
__device__ __forceinline__ unsigned short f2bf(float f) {
  union { float f; u32 i; } v; v.f = f;
  u32 x = v.i;
  u32 r = (x + 0x7FFFu + ((x >> 16) & 1u)) >> 16;
  return (unsigned short)r;
}

__device__ __forceinline__ void gload_lds16(const unsigned short* g, unsigned short* l) {
  __builtin_amdgcn_global_load_lds((const __attribute__((address_space(1))) u32*)(g),
                                   (__attribute__((address_space(3))) u32*)(l), 16, 0, 0);
}

__device__ __forceinline__ void wave_bar() {
  asm volatile("" ::: "memory");
  __builtin_amdgcn_s_barrier();
  asm volatile("" ::: "memory");
}

// ---------------- K0 fused: prep W' / permute-cast Wo / mask-norm scale ----------------
__global__ __launch_bounds__(256) void
fused_prep_kernel(const float* __restrict__ Wa, const float* __restrict__ ba,
                  const float* __restrict__ Wb, const float* __restrict__ bb,
                  const float* __restrict__ ln_g, const float* __restrict__ ln_b,
                  const float* __restrict__ Wo, const float* __restrict__ mask,
                  unsigned short* __restrict__ wp, float* __restrict__ Ka,
                  float* __restrict__ Ca, unsigned short* __restrict__ Wo_bf,
                  float* __restrict__ scale) {
  const int b = blockIdx.x;
  const int t = threadIdx.x;
  if (b < 64) {
    __shared__ float ska[4], sca[4];
    const int o = b;
    const float* W = (o < 32) ? (Wa + o * CM) : (Wb + (o - 32) * CM);
    float wv = W[t];
    unsigned short bv = f2bf(wv * ln_g[t]);
    wp[o * CM + t] = bv;
    float ka = bf2f(bv);
    float ca = wv * ln_b[t];
    #pragma unroll
    for (int m = 1; m < 64; m <<= 1) {
      ka += __shfl_xor(ka, m);
      ca += __shfl_xor(ca, m);
    }
    if ((t & 63) == 0) { ska[t >> 6] = ka; sca[t >> 6] = ca; }
    __syncthreads();
    if (t == 0) {
      Ka[o] = ska[0] + ska[1] + ska[2] + ska[3];
      Ca[o] = sca[0] + sca[1] + sca[2] + sca[3] + ((o < 32) ? ba[o] : bb[o - 32]);
    }
  } else if (b < 576) {
    // Wo cast + transpose to k' = e*32+d (matches epilogue O layout)
    int idx = (b - 64) * 256 + t;
    int z = idx >> 10, k = idx & 1023;
    int d = k >> 5, e = k & 31;
    Wo_bf[(z << 10) + e * 32 + d] = f2bf(Wo[idx]);
  } else {
    const int i = b - 576, j = t;
    float sum = 0.f;
    for (int s = 0; s < S_DIM; ++s)
      sum += mask[s * R_DIM + i] * mask[s * R_DIM + j];
    scale[i * R_DIM + j] = 1.0f / (1e-3f + sum);
  }
}

// ---------------- K1: fused LN + projections -> leftT/rightT bf16 [8192][512] ----------------
#define K1_ROWS 64
#define XPAD 264

__global__ __launch_bounds__(256) void
ln_proj_kernel(const float* __restrict__ M, const float* __restrict__ mask,
               const unsigned short* __restrict__ wp_g, const float* __restrict__ Ka_g,
               const float* __restrict__ Ca_g,
               unsigned short* __restrict__ leftT, unsigned short* __restrict__ rightT) {
  __shared__ unsigned short xt[K1_ROWS * XPAD];
  __shared__ unsigned short wp[64 * XPAD];
  __shared__ float smu[K1_ROWS], srs[K1_ROWS], smk[K1_ROWS];
  __shared__ float sKa[64], sCa[64];

  const int t = threadIdx.x;
  const int lane = t & 63;
  const int w = t >> 6;
  const int lm = lane & 15;
  const int rr = lane >> 4;
  const int i = blockIdx.x;
  const int s0 = blockIdx.y * K1_ROWS;

  for (int idx = t; idx < 64 * CM / 8; idx += 256) {
    int row = idx >> 5;
    int col = (idx & 31) * 8;
    *(uint4*)(&wp[row * XPAD + col]) = *(const uint4*)(wp_g + row * CM + col);
  }
  if (t < 64) { sKa[t] = Ka_g[t]; sCa[t] = Ca_g[t]; }

  #pragma unroll
  for (int it = 0; it < 4; ++it) {
    const int row = w * 16 + it * 4 + rr;
    const int sg = s0 + row;
    const float* src = M + ((size_t)sg * R_DIM + i) * CM;
    float4 x[4];
    #pragma unroll
    for (int ch = 0; ch < 4; ++ch) x[ch] = *(const float4*)(src + ch * 64 + lm * 4);
    float sum = 0.f, ssq = 0.f;
    #pragma unroll
    for (int ch = 0; ch < 4; ++ch) {
      sum += x[ch].x + x[ch].y + x[ch].z + x[ch].w;
      ssq += x[ch].x * x[ch].x + x[ch].y * x[ch].y + x[ch].z * x[ch].z + x[ch].w * x[ch].w;
    }
    #pragma unroll
    for (int m = 1; m < 16; m <<= 1) {
      sum += __shfl_xor(sum, m);
      ssq += __shfl_xor(ssq, m);
    }
    float mu = sum * (1.0f / CM);
    float var = ssq * (1.0f / CM) - mu * mu;
    float rs = rsqrtf(var + 1e-5f);
    if (lm == 0) {
      smu[row] = mu; srs[row] = rs;
      smk[row] = mask[(size_t)sg * R_DIM + i];
    }
    #pragma unroll
    for (int ch = 0; ch < 4; ++ch) {
      ushort4 xb;
      xb.x = f2bf(x[ch].x); xb.y = f2bf(x[ch].y); xb.z = f2bf(x[ch].z); xb.w = f2bf(x[ch].w);
      *(ushort4*)(&xt[row * XPAD + ch * 64 + lm * 4]) = xb;
    }
  }
  __syncthreads();

  f32x4 acc[4] = {{0.f, 0.f, 0.f, 0.f}, {0.f, 0.f, 0.f, 0.f},
                  {0.f, 0.f, 0.f, 0.f}, {0.f, 0.f, 0.f, 0.f}};
  #pragma unroll
  for (int k = 0; k < 8; ++k) {
    const int c0 = k * 32 + ((lane >> 4) << 3);
    bf16x8 a = *(const bf16x8*)(&wp[(w * 16 + (lane & 15)) * XPAD + c0]);
    #pragma unroll
    for (int nt = 0; nt < 4; ++nt) {
      bf16x8 b = *(const bf16x8*)(&xt[(nt * 16 + (lane & 15)) * XPAD + c0]);
      acc[nt] = __builtin_amdgcn_mfma_f32_16x16x32_bf16(a, b, acc[nt], 0, 0, 0);
    }
  }

  #pragma unroll
  for (int nt = 0; nt < 4; ++nt) {
    int srow = nt * 16 + (lane & 15);
    float mu = smu[srow], rs = srs[srow], mk = smk[srow];
    int sg = s0 + srow;
    #pragma unroll
    for (int r = 0; r < 4; ++r) {
      int o = w * 16 + ((lane >> 4) << 2) + r;
      float v = (rs * (acc[nt][r] - mu * sKa[o]) + sCa[o]) * mk;
      unsigned short bv = f2bf(v);
      if (o < 32) leftT[(size_t)(i * 32 + o) * S_DIM + sg] = bv;
      else        rightT[(size_t)(i * 32 + (o - 32)) * S_DIM + sg] = bv;
    }
  }
}

// ---------------- K2: 256x256 tile, k-major LDS, 32x32x16 MFMA, dbuf + fused Wo ----------------
// LDS per buffer: A [8 ksu][256 row] 16B-units (32KB) + B same (32KB); 2 buffers = 128KB.
// Reads are 32-lane-contiguous (conflict-free, zero swizzle). 2 barriers/K-tile, vmcnt(8).
#define NT2 8   // 512 / 64 K-tiles

__global__ __launch_bounds__(512, 1) void
opm_gemm_kernel(const unsigned short* __restrict__ leftT, const unsigned short* __restrict__ rightT,
                const unsigned short* __restrict__ Wo_bf, const float* __restrict__ bo,
                const float* __restrict__ scale, float* __restrict__ out) {
  extern __shared__ unsigned short smem[];  // 65536 shorts = 128 KiB

  const int t = threadIdx.x;
  const int lane = t & 63;
  const int l31 = lane & 31, lq2 = lane >> 5;
  const int w = t >> 6;            // 0..7
  const int wm = w >> 2, wn = w & 3;

  // XCD chunk = 128 blocks; within chunk bx-major: A panels L2-resident
  const int bid = blockIdx.x;
  const int xcd = bid & 7, local = bid >> 3;
  const int by = xcd * 4 + (local & 3);
  const int bx = local >> 2;

  const unsigned short* Asrc = leftT + (size_t)(by * 256) * S_DIM;
  const unsigned short* Bsrc = rightT + (size_t)(bx * 256) * S_DIM;

  // k-major staging decode: chunk c -> LDS 16B-unit c (plane ksu=c>>8, row=c&255)
  // global element offset = row*512 + ksu*8 (+ kb per tile)
  int aoff[4], ldso[4];
  #pragma unroll
  for (int q = 0; q < 4; ++q) {
    int c = q * 512 + t;
    aoff[q] = (c & 255) * S_DIM + (c >> 8) * 8;
    ldso[q] = c * 8;
  }

  f32x16 acc[4][2];
  #pragma unroll
  for (int a = 0; a < 4; ++a)
    #pragma unroll
    for (int b = 0; b < 2; ++b)
      #pragma unroll
      for (int r = 0; r < 16; ++r) acc[a][b][r] = 0.f;

  auto STAGE = [&](int kt, int buf) {
    const int kb = kt * 64;
    unsigned short* ab = smem + buf * 32768;
    #pragma unroll
    for (int q = 0; q < 4; ++q) {
      gload_lds16(Asrc + aoff[q] + kb, ab + ldso[q]);
      gload_lds16(Bsrc + aoff[q] + kb, ab + 16384 + ldso[q]);
    }
  };

  STAGE(0, 0);
  STAGE(1, 1);

  // per-wave row offsets (shorts)
  int arow[4], brow[2];
  #pragma unroll
  for (int mi = 0; mi < 4; ++mi) arow[mi] = (wm * 128 + mi * 32 + l31) * 8;
  #pragma unroll
  for (int ni = 0; ni < 2; ++ni) brow[ni] = 16384 + (wn * 64 + ni * 32 + l31) * 8;

  for (int kt = 0; kt < NT2; ++kt) {
    if (kt < NT2 - 1) asm volatile("s_waitcnt vmcnt(8)" ::: "memory");
    else              asm volatile("s_waitcnt vmcnt(0)" ::: "memory");
    wave_bar();

    const unsigned short* Ab = smem + (kt & 1) * 32768;
    #pragma unroll
    for (int ks = 0; ks < 4; ++ks) {
      const int kbase = (ks * 2 + lq2) * 2048;
      bf16x8 af[4], bf[2];
      #pragma unroll
      for (int mi = 0; mi < 4; ++mi) af[mi] = *(const bf16x8*)(Ab + kbase + arow[mi]);
      #pragma unroll
      for (int ni = 0; ni < 2; ++ni) bf[ni] = *(const bf16x8*)(Ab + kbase + brow[ni]);
      #pragma unroll
      for (int mi = 0; mi < 4; ++mi)
        #pragma unroll
        for (int ni = 0; ni < 2; ++ni)
          acc[mi][ni] = __builtin_amdgcn_mfma_f32_32x32x16_bf16(af[mi], bf[ni], acc[mi][ni], 0, 0, 0);
    }

    wave_bar();
    if (kt + 2 < NT2) STAGE(kt + 2, kt & 1);
  }

  // ---- epilogue part 1: acc -> O k-major [ksu 0..127][pair 0..63] 16B entries,
  //      entry swizzle phys = pair ^ (ksu>>2); b64 writes ----
  #pragma unroll
  for (int mi = 0; mi < 4; ++mi) {
    #pragma unroll
    for (int ni = 0; ni < 2; ++ni) {
      const int pair = (wm * 4 + mi) * 8 + wn * 2 + ni;
      const u32 pbyte = (u32)((pair ^ l31) * 16 + lq2 * 8);
      #pragma unroll
      for (int g = 0; g < 4; ++g) {
        const u32 byte = (u32)(l31 * 4 + g) * 1024 + pbyte;
        ushort4 v4;
        v4.x = f2bf(acc[mi][ni][g * 4 + 0]);
        v4.y = f2bf(acc[mi][ni][g * 4 + 1]);
        v4.z = f2bf(acc[mi][ni][g * 4 + 2]);
        v4.w = f2bf(acc[mi][ni][g * 4 + 3]);
        *(ushort4*)((char*)smem + byte) = v4;
      }
    }
  }
  __syncthreads();

  // ---- epilogue part 2: Z[pair][z] = O . Wo_perm  (wave: 32 pairs (wm) x 32 z (wn), K=1024) ----
  f32x16 zacc;
  #pragma unroll
  for (int r = 0; r < 16; ++r) zacc[r] = 0.f;
  const unsigned short* wop = Wo_bf + (size_t)(wn * 32 + l31) * (CP * CP) + lq2 * 8;
  #pragma unroll 4
  for (int kk = 0; kk < 64; ++kk) {
    bf16x8 bw = *(const bf16x8*)(wop + kk * 16);
    const u32 ob = (u32)(kk * 2 + lq2) * 1024 + (u32)(((wm * 32 + l31) ^ (kk >> 1)) * 16);
    bf16x8 oa = *(const bf16x8*)((const char*)smem + ob);
    zacc = __builtin_amdgcn_mfma_f32_32x32x16_bf16(oa, bw, zacc, 0, 0, 0);
  }

  const int z = wn * 32 + l31;
  const float bz = bo[z];
  #pragma unroll
  for (int r = 0; r < 16; ++r) {
    const int pair = wm * 32 + (r & 3) + 8 * (r >> 2) + 4 * lq2;
    const int ig = by * 8 + (pair >> 3), jg = bx * 8 + (pair & 7);
    float v = (zacc[r] + bz) * scale[ig * R_DIM + jg];
    out[((size_t)ig * R_DIM + jg) * CZ + z] = v;
  }
}

extern "C" void kernel_launch(void* const* d_in, const int* in_sizes, int n_in,
                              void* d_out, int out_size, void* d_ws, size_t ws_size,
                              hipStream_t stream) {
  const float* M     = (const float*)d_in[0];
  const float* Mmask = (const float*)d_in[1];
  const float* ln_g  = (const float*)d_in[3];
  const float* ln_b  = (const float*)d_in[4];
  const float* Wa    = (const float*)d_in[5];
  const float* ba    = (const float*)d_in[6];
  const float* Wb    = (const float*)d_in[7];
  const float* bb    = (const float*)d_in[8];
  const float* Wo    = (const float*)d_in[9];
  const float* bo    = (const float*)d_in[10];
  float* out = (float*)d_out;

  char* ws = (char*)d_ws;
  unsigned short* leftT  = (unsigned short*)(ws);
  unsigned short* rightT = (unsigned short*)(ws + 8388608);
  unsigned short* wp     = (unsigned short*)(ws + 16777216);
  float*          Ka     = (float*)(ws + 16810240);
  float*          Ca     = (float*)(ws + 16810496);
  unsigned short* Wo_bf  = (unsigned short*)(ws + 16810752);
  float*          scale  = (float*)(ws + 17072896);
  (void)ws_size; (void)in_sizes; (void)n_in; (void)out_size;

  hipFuncSetAttribute((const void*)opm_gemm_kernel,
                      hipFuncAttributeMaxDynamicSharedMemorySize, 131072);

  hipLaunchKernelGGL(fused_prep_kernel, dim3(832), dim3(256), 0, stream,
                     Wa, ba, Wb, bb, ln_g, ln_b, Wo, Mmask, wp, Ka, Ca, Wo_bf, scale);
  hipLaunchKernelGGL(ln_proj_kernel, dim3(R_DIM, S_DIM / K1_ROWS), dim3(256), 0, stream,
                     M, Mmask, wp, Ka, Ca, leftT, rightT);
  hipLaunchKernelGGL(opm_gemm_kernel, dim3(1024), dim3(512), 131072, stream,
                     leftT, rightT, Wo_bf, bo, scale, out);
}

// Round 8
// 187.986 us; speedup vs baseline: 1.4033x; 1.4033x over previous
//
#include <hip/hip_runtime.h>
#include <hip/hip_bf16.h>
#include <stdint.h>

// OuterProductMean: B=1, S=512, R=256, C_M=256, C_P=32, C_Z=128
#define S_DIM 512
#define R_DIM 256
#define CM 256
#define CP 32
#define CZ 128

typedef __attribute__((ext_vector_type(8))) short bf16x8;
typedef __attribute__((ext_vector_type(4))) float f32x4;
typedef __attribute__((ext_vector_type(16))) float f32x16;
typedef unsigned int u32;

__device__ __forceinline__ float bf2f(unsigned short u) {
  union { u32 i; float f; } v; v.i = ((u32)u) << 16; return v.f;
}
__device__ __forceinline__ unsigned short f2bf(float f) {
  union { float f; u32 i; } v; v.f = f;
  u32 x = v.i;
  u32 r = (x + 0x7FFFu + ((x >> 16) & 1u)) >> 16;
  return (unsigned short)r;
}

__device__ __forceinline__ void gload_lds16(const unsigned short* g, unsigned short* l) {
  __builtin_amdgcn_global_load_lds((const __attribute__((address_space(1))) u32*)(g),
                                   (__attribute__((address_space(3))) u32*)(l), 16, 0, 0);
}

__device__ __forceinline__ void wave_bar() {
  asm volatile("" ::: "memory");
  __builtin_amdgcn_s_barrier();
  asm volatile("" ::: "memory");
}

// ---------------- K0 fused: prep W' / permute-cast Wo / mask-norm scale ----------------
__global__ __launch_bounds__(256) void
fused_prep_kernel(const float* __restrict__ Wa, const float* __restrict__ ba,
                  const float* __restrict__ Wb, const float* __restrict__ bb,
                  const float* __restrict__ ln_g, const float* __restrict__ ln_b,
                  const float* __restrict__ Wo, const float* __restrict__ mask,
                  unsigned short* __restrict__ wp, float* __restrict__ Ka,
                  float* __restrict__ Ca, unsigned short* __restrict__ Wo_bf,
                  float* __restrict__ scale) {
  const int b = blockIdx.x;
  const int t = threadIdx.x;
  if (b < 64) {
    __shared__ float ska[4], sca[4];
    const int o = b;
    const float* W = (o < 32) ? (Wa + o * CM) : (Wb + (o - 32) * CM);
    float wv = W[t];
    unsigned short bv = f2bf(wv * ln_g[t]);
    wp[o * CM + t] = bv;
    float ka = bf2f(bv);
    float ca = wv * ln_b[t];
    #pragma unroll
    for (int m = 1; m < 64; m <<= 1) {
      ka += __shfl_xor(ka, m);
      ca += __shfl_xor(ca, m);
    }
    if ((t & 63) == 0) { ska[t >> 6] = ka; sca[t >> 6] = ca; }
    __syncthreads();
    if (t == 0) {
      Ka[o] = ska[0] + ska[1] + ska[2] + ska[3];
      Ca[o] = sca[0] + sca[1] + sca[2] + sca[3] + ((o < 32) ? ba[o] : bb[o - 32]);
    }
  } else if (b < 576) {
    // Wo cast + transpose to k' = e*32+d (matches epilogue O layout)
    int idx = (b - 64) * 256 + t;
    int z = idx >> 10, k = idx & 1023;
    int d = k >> 5, e = k & 31;
    Wo_bf[(z << 10) + e * 32 + d] = f2bf(Wo[idx]);
  } else {
    const int i = b - 576, j = t;
    float sum = 0.f;
    for (int s = 0; s < S_DIM; ++s)
      sum += mask[s * R_DIM + i] * mask[s * R_DIM + j];
    scale[i * R_DIM + j] = 1.0f / (1e-3f + sum);
  }
}

// ---------------- K1: fused LN + projections -> left/right k-blocked bf16 ----------------
// output layout: [ksu = s/8][row = i*32+d][8 s-sub]  (65536 shorts per ksu plane)
#define K1_ROWS 64
#define XPAD 264

__global__ __launch_bounds__(256) void
ln_proj_kernel(const float* __restrict__ M, const float* __restrict__ mask,
               const unsigned short* __restrict__ wp_g, const float* __restrict__ Ka_g,
               const float* __restrict__ Ca_g,
               unsigned short* __restrict__ leftT, unsigned short* __restrict__ rightT) {
  __shared__ unsigned short xt[K1_ROWS * XPAD];
  __shared__ unsigned short wp[64 * XPAD];
  __shared__ float smu[K1_ROWS], srs[K1_ROWS], smk[K1_ROWS];
  __shared__ float sKa[64], sCa[64];

  const int t = threadIdx.x;
  const int lane = t & 63;
  const int w = t >> 6;
  const int lm = lane & 15;
  const int rr = lane >> 4;
  const int i = blockIdx.x;
  const int s0 = blockIdx.y * K1_ROWS;

  for (int idx = t; idx < 64 * CM / 8; idx += 256) {
    int row = idx >> 5;
    int col = (idx & 31) * 8;
    *(uint4*)(&wp[row * XPAD + col]) = *(const uint4*)(wp_g + row * CM + col);
  }
  if (t < 64) { sKa[t] = Ka_g[t]; sCa[t] = Ca_g[t]; }

  #pragma unroll
  for (int it = 0; it < 4; ++it) {
    const int row = w * 16 + it * 4 + rr;
    const int sg = s0 + row;
    const float* src = M + ((size_t)sg * R_DIM + i) * CM;
    float4 x[4];
    #pragma unroll
    for (int ch = 0; ch < 4; ++ch) x[ch] = *(const float4*)(src + ch * 64 + lm * 4);
    float sum = 0.f, ssq = 0.f;
    #pragma unroll
    for (int ch = 0; ch < 4; ++ch) {
      sum += x[ch].x + x[ch].y + x[ch].z + x[ch].w;
      ssq += x[ch].x * x[ch].x + x[ch].y * x[ch].y + x[ch].z * x[ch].z + x[ch].w * x[ch].w;
    }
    #pragma unroll
    for (int m = 1; m < 16; m <<= 1) {
      sum += __shfl_xor(sum, m);
      ssq += __shfl_xor(ssq, m);
    }
    float mu = sum * (1.0f / CM);
    float var = ssq * (1.0f / CM) - mu * mu;
    float rs = rsqrtf(var + 1e-5f);
    if (lm == 0) {
      smu[row] = mu; srs[row] = rs;
      smk[row] = mask[(size_t)sg * R_DIM + i];
    }
    #pragma unroll
    for (int ch = 0; ch < 4; ++ch) {
      ushort4 xb;
      xb.x = f2bf(x[ch].x); xb.y = f2bf(x[ch].y); xb.z = f2bf(x[ch].z); xb.w = f2bf(x[ch].w);
      *(ushort4*)(&xt[row * XPAD + ch * 64 + lm * 4]) = xb;
    }
  }
  __syncthreads();

  f32x4 acc[4] = {{0.f, 0.f, 0.f, 0.f}, {0.f, 0.f, 0.f, 0.f},
                  {0.f, 0.f, 0.f, 0.f}, {0.f, 0.f, 0.f, 0.f}};
  #pragma unroll
  for (int k = 0; k < 8; ++k) {
    const int c0 = k * 32 + ((lane >> 4) << 3);
    bf16x8 a = *(const bf16x8*)(&wp[(w * 16 + (lane & 15)) * XPAD + c0]);
    #pragma unroll
    for (int nt = 0; nt < 4; ++nt) {
      bf16x8 b = *(const bf16x8*)(&xt[(nt * 16 + (lane & 15)) * XPAD + c0]);
      acc[nt] = __builtin_amdgcn_mfma_f32_16x16x32_bf16(a, b, acc[nt], 0, 0, 0);
    }
  }

  // store k-blocked: dst = (sg>>3)*65536 + row*8 + (sg&7)
  #pragma unroll
  for (int nt = 0; nt < 4; ++nt) {
    int srow = nt * 16 + (lane & 15);
    float mu = smu[srow], rs = srs[srow], mk = smk[srow];
    int sg = s0 + srow;
    const size_t base = (size_t)(sg >> 3) * 65536 + (sg & 7);
    #pragma unroll
    for (int r = 0; r < 4; ++r) {
      int o = w * 16 + ((lane >> 4) << 2) + r;
      float v = (rs * (acc[nt][r] - mu * sKa[o]) + sCa[o]) * mk;
      unsigned short bv = f2bf(v);
      if (o < 32) leftT[base + (size_t)(i * 32 + o) * 8] = bv;
      else        rightT[base + (size_t)(i * 32 + (o - 32)) * 8] = bv;
    }
  }
}

// ---------------- K2: 256x256 tile, k-blocked global + k-major LDS, 32x32x16 MFMA ----------------
// Staging: 1KB contiguous per wave-gload (global k-blocked), LDS [ksu][row] conflict-free reads.
// 2 barriers/K-tile, counted vmcnt(8), prefetch distance 2 tiles. Fused Wo epilogue.
#define NT2 8   // 512 / 64 K-tiles

__global__ __launch_bounds__(512, 1) void
opm_gemm_kernel(const unsigned short* __restrict__ leftT, const unsigned short* __restrict__ rightT,
                const unsigned short* __restrict__ Wo_bf, const float* __restrict__ bo,
                const float* __restrict__ scale, float* __restrict__ out) {
  extern __shared__ unsigned short smem[];  // 65536 shorts = 128 KiB

  const int t = threadIdx.x;
  const int lane = t & 63;
  const int l31 = lane & 31, lq2 = lane >> 5;
  const int w = t >> 6;            // 0..7
  const int wm = w >> 2, wn = w & 3;

  // XCD chunk = 128 blocks; within chunk bx-major: A panels L2-resident
  const int bid = blockIdx.x;
  const int xcd = bid & 7, local = bid >> 3;
  const int by = xcd * 4 + (local & 3);
  const int bx = local >> 2;

  // k-blocked global: plane ksu (65536 shorts) x row x 8
  const unsigned short* Asrc = leftT + (size_t)(by * 256) * 8;
  const unsigned short* Bsrc = rightT + (size_t)(bx * 256) * 8;

  // staging unit u = c: plane p = c>>8 (local ksu), row r = c&255
  // global ofs = p*65536 + r*8 (+ kt*8 planes); LDS dest = c*8 shorts. Fully linear both sides.
  int aoff[4], ldso[4];
  #pragma unroll
  for (int q = 0; q < 4; ++q) {
    int c = q * 512 + t;
    aoff[q] = (c >> 8) * 65536 + (c & 255) * 8;
    ldso[q] = c * 8;
  }

  f32x16 acc[4][2];
  #pragma unroll
  for (int a = 0; a < 4; ++a)
    #pragma unroll
    for (int b = 0; b < 2; ++b)
      #pragma unroll
      for (int r = 0; r < 16; ++r) acc[a][b][r] = 0.f;

  auto STAGE = [&](int kt, int buf) {
    const size_t kb = (size_t)kt * 8 * 65536;
    unsigned short* ab = smem + buf * 32768;
    #pragma unroll
    for (int q = 0; q < 4; ++q) {
      gload_lds16(Asrc + kb + aoff[q], ab + ldso[q]);
      gload_lds16(Bsrc + kb + aoff[q], ab + 16384 + ldso[q]);
    }
  };

  STAGE(0, 0);
  STAGE(1, 1);

  // per-wave row offsets (shorts) within a plane
  int arow[4], brow[2];
  #pragma unroll
  for (int mi = 0; mi < 4; ++mi) arow[mi] = (wm * 128 + mi * 32 + l31) * 8;
  #pragma unroll
  for (int ni = 0; ni < 2; ++ni) brow[ni] = 16384 + (wn * 64 + ni * 32 + l31) * 8;

  for (int kt = 0; kt < NT2; ++kt) {
    if (kt < NT2 - 1) asm volatile("s_waitcnt vmcnt(8)" ::: "memory");
    else              asm volatile("s_waitcnt vmcnt(0)" ::: "memory");
    wave_bar();

    const unsigned short* Ab = smem + (kt & 1) * 32768;
    #pragma unroll
    for (int ks = 0; ks < 4; ++ks) {
      const int kbase = (ks * 2 + lq2) * 2048;   // plane = ks*2+lq2 (2048 shorts/plane)
      bf16x8 af[4], bf[2];
      #pragma unroll
      for (int mi = 0; mi < 4; ++mi) af[mi] = *(const bf16x8*)(Ab + kbase + arow[mi]);
      #pragma unroll
      for (int ni = 0; ni < 2; ++ni) bf[ni] = *(const bf16x8*)(Ab + kbase + brow[ni]);
      #pragma unroll
      for (int mi = 0; mi < 4; ++mi)
        #pragma unroll
        for (int ni = 0; ni < 2; ++ni)
          acc[mi][ni] = __builtin_amdgcn_mfma_f32_32x32x16_bf16(af[mi], bf[ni], acc[mi][ni], 0, 0, 0);
    }

    wave_bar();
    if (kt + 2 < NT2) STAGE(kt + 2, kt & 1);
  }

  // ---- epilogue part 1: acc -> O k-major [k-group 0..127][pair 0..63] 16B entries,
  //      entry swizzle phys = pair ^ (plane>>2); b64 writes ----
  #pragma unroll
  for (int mi = 0; mi < 4; ++mi) {
    #pragma unroll
    for (int ni = 0; ni < 2; ++ni) {
      const int pair = (wm * 4 + mi) * 8 + wn * 2 + ni;
      const u32 pbyte = (u32)((pair ^ l31) * 16 + lq2 * 8);
      #pragma unroll
      for (int g = 0; g < 4; ++g) {
        const u32 byte = (u32)(l31 * 4 + g) * 1024 + pbyte;
        ushort4 v4;
        v4.x = f2bf(acc[mi][ni][g * 4 + 0]);
        v4.y = f2bf(acc[mi][ni][g * 4 + 1]);
        v4.z = f2bf(acc[mi][ni][g * 4 + 2]);
        v4.w = f2bf(acc[mi][ni][g * 4 + 3]);
        *(ushort4*)((char*)smem + byte) = v4;
      }
    }
  }
  __syncthreads();

  // ---- epilogue part 2: Z[pair][z] = O . Wo_perm  (wave: 32 pairs (wm) x 32 z (wn), K=1024) ----
  f32x16 zacc;
  #pragma unroll
  for (int r = 0; r < 16; ++r) zacc[r] = 0.f;
  const unsigned short* wop = Wo_bf + (size_t)(wn * 32 + l31) * (CP * CP) + lq2 * 8;
  #pragma unroll 4
  for (int kk = 0; kk < 64; ++kk) {
    bf16x8 bw = *(const bf16x8*)(wop + kk * 16);
    const u32 ob = (u32)(kk * 2 + lq2) * 1024 + (u32)(((wm * 32 + l31) ^ (kk >> 1)) * 16);
    bf16x8 oa = *(const bf16x8*)((const char*)smem + ob);
    zacc = __builtin_amdgcn_mfma_f32_32x32x16_bf16(oa, bw, zacc, 0, 0, 0);
  }

  const int z = wn * 32 + l31;
  const float bz = bo[z];
  #pragma unroll
  for (int r = 0; r < 16; ++r) {
    const int pair = wm * 32 + (r & 3) + 8 * (r >> 2) + 4 * lq2;
    const int ig = by * 8 + (pair >> 3), jg = bx * 8 + (pair & 7);
    float v = (zacc[r] + bz) * scale[ig * R_DIM + jg];
    out[((size_t)ig * R_DIM + jg) * CZ + z] = v;
  }
}

extern "C" void kernel_launch(void* const* d_in, const int* in_sizes, int n_in,
                              void* d_out, int out_size, void* d_ws, size_t ws_size,
                              hipStream_t stream) {
  const float* M     = (const float*)d_in[0];
  const float* Mmask = (const float*)d_in[1];
  const float* ln_g  = (const float*)d_in[3];
  const float* ln_b  = (const float*)d_in[4];
  const float* Wa    = (const float*)d_in[5];
  const float* ba    = (const float*)d_in[6];
  const float* Wb    = (const float*)d_in[7];
  const float* bb    = (const float*)d_in[8];
  const float* Wo    = (const float*)d_in[9];
  const float* bo    = (const float*)d_in[10];
  float* out = (float*)d_out;

  char* ws = (char*)d_ws;
  unsigned short* leftT  = (unsigned short*)(ws);
  unsigned short* rightT = (unsigned short*)(ws + 8388608);
  unsigned short* wp     = (unsigned short*)(ws + 16777216);
  float*          Ka     = (float*)(ws + 16810240);
  float*          Ca     = (float*)(ws + 16810496);
  unsigned short* Wo_bf  = (unsigned short*)(ws + 16810752);
  float*          scale  = (float*)(ws + 17072896);
  (void)ws_size; (void)in_sizes; (void)n_in; (void)out_size;

  hipFuncSetAttribute((const void*)opm_gemm_kernel,
                      hipFuncAttributeMaxDynamicSharedMemorySize, 131072);

  hipLaunchKernelGGL(fused_prep_kernel, dim3(832), dim3(256), 0, stream,
                     Wa, ba, Wb, bb, ln_g, ln_b, Wo, Mmask, wp, Ka, Ca, Wo_bf, scale);
  hipLaunchKernelGGL(ln_proj_kernel, dim3(R_DIM, S_DIM / K1_ROWS), dim3(256), 0, stream,
                     M, Mmask, wp, Ka, Ca, leftT, rightT);
  hipLaunchKernelGGL(opm_gemm_kernel, dim3(1024), dim3(512), 131072, stream,
                     leftT, rightT, Wo_bf, bo, scale, out);
}

// Round 9
// 165.630 us; speedup vs baseline: 1.5927x; 1.1350x over previous
//
#include <hip/hip_runtime.h>
#include <hip/hip_bf16.h>
#include <stdint.h>

// OuterProductMean: B=1, S=512, R=256, C_M=256, C_P=32, C_Z=128
#define S_DIM 512
#define R_DIM 256
#define CM 256
#define CP 32
#define CZ 128

typedef __attribute__((ext_vector_type(8))) short bf16x8;
typedef __attribute__((ext_vector_type(4))) float f32x4;
typedef __attribute__((ext_vector_type(16))) float f32x16;
typedef unsigned int u32;

__device__ __forceinline__ float bf2f(unsigned short u) {
  union { u32 i; float f; } v; v.i = ((u32)u) << 16; return v.f;
}
__device__ __forceinline__ unsigned short f2bf(float f) {
  union { float f; u32 i; } v; v.f = f;
  u32 x = v.i;
  u32 r = (x + 0x7FFFu + ((x >> 16) & 1u)) >> 16;
  return (unsigned short)r;
}

__device__ __forceinline__ void gload_lds16(const unsigned short* g, unsigned short* l) {
  __builtin_amdgcn_global_load_lds((const __attribute__((address_space(1))) u32*)(g),
                                   (__attribute__((address_space(3))) u32*)(l), 16, 0, 0);
}

__device__ __forceinline__ void wave_bar() {
  asm volatile("" ::: "memory");
  __builtin_amdgcn_s_barrier();
  asm volatile("" ::: "memory");
}

// ---------------- K0 fused: prep W' / k-major-cast Wo / mask-norm scale ----------------
__global__ __launch_bounds__(256) void
fused_prep_kernel(const float* __restrict__ Wa, const float* __restrict__ ba,
                  const float* __restrict__ Wb, const float* __restrict__ bb,
                  const float* __restrict__ ln_g, const float* __restrict__ ln_b,
                  const float* __restrict__ Wo, const float* __restrict__ mask,
                  unsigned short* __restrict__ wp, float* __restrict__ Ka,
                  float* __restrict__ Ca, unsigned short* __restrict__ Wo_bf,
                  float* __restrict__ scale) {
  const int b = blockIdx.x;
  const int t = threadIdx.x;
  if (b < 64) {
    __shared__ float ska[4], sca[4];
    const int o = b;
    const float* W = (o < 32) ? (Wa + o * CM) : (Wb + (o - 32) * CM);
    float wv = W[t];
    unsigned short bv = f2bf(wv * ln_g[t]);
    wp[o * CM + t] = bv;
    float ka = bf2f(bv);
    float ca = wv * ln_b[t];
    #pragma unroll
    for (int m = 1; m < 64; m <<= 1) {
      ka += __shfl_xor(ka, m);
      ca += __shfl_xor(ca, m);
    }
    if ((t & 63) == 0) { ska[t >> 6] = ka; sca[t >> 6] = ca; }
    __syncthreads();
    if (t == 0) {
      Ka[o] = ska[0] + ska[1] + ska[2] + ska[3];
      Ca[o] = sca[0] + sca[1] + sca[2] + sca[3] + ((o < 32) ? ba[o] : bb[o - 32]);
    }
  } else if (b < 576) {
    // Wo -> bf16, transposed k' = e*32+d, stored k-major: [k'>>3 plane][z][k'&7]
    int idx = (b - 64) * 256 + t;
    int z = idx >> 10, k = idx & 1023;
    int d = k >> 5, e = k & 31;
    int kp = e * 32 + d;
    Wo_bf[(kp >> 3) * 1024 + z * 8 + (kp & 7)] = f2bf(Wo[idx]);
  } else {
    const int i = b - 576, j = t;
    float sum = 0.f;
    for (int s = 0; s < S_DIM; ++s)
      sum += mask[s * R_DIM + i] * mask[s * R_DIM + j];
    scale[i * R_DIM + j] = 1.0f / (1e-3f + sum);
  }
}

// ---------------- K1: fused LN + projections -> left/right k-blocked bf16 ----------------
// output layout: [plane = s/8][row = i*32+o][8 s-sub]  (65536 shorts per plane)
#define K1_ROWS 64
#define XPAD 264
#define OTP 72   // ot row stride (shorts)

__global__ __launch_bounds__(256) void
ln_proj_kernel(const float* __restrict__ M, const float* __restrict__ mask,
               const unsigned short* __restrict__ wp_g, const float* __restrict__ Ka_g,
               const float* __restrict__ Ca_g,
               unsigned short* __restrict__ leftT, unsigned short* __restrict__ rightT) {
  __shared__ unsigned short xt[K1_ROWS * XPAD];
  __shared__ unsigned short wp[64 * XPAD];
  __shared__ unsigned short ot[64 * OTP];   // [o][s] transpose buffer
  __shared__ float smu[K1_ROWS], srs[K1_ROWS], smk[K1_ROWS];
  __shared__ float sKa[64], sCa[64];

  const int t = threadIdx.x;
  const int lane = t & 63;
  const int w = t >> 6;
  const int lm = lane & 15;
  const int rr = lane >> 4;
  const int i = blockIdx.x;
  const int s0 = blockIdx.y * K1_ROWS;

  for (int idx = t; idx < 64 * CM / 8; idx += 256) {
    int row = idx >> 5;
    int col = (idx & 31) * 8;
    *(uint4*)(&wp[row * XPAD + col]) = *(const uint4*)(wp_g + row * CM + col);
  }
  if (t < 64) { sKa[t] = Ka_g[t]; sCa[t] = Ca_g[t]; }

  #pragma unroll
  for (int it = 0; it < 4; ++it) {
    const int row = w * 16 + it * 4 + rr;
    const int sg = s0 + row;
    const float* src = M + ((size_t)sg * R_DIM + i) * CM;
    float4 x[4];
    #pragma unroll
    for (int ch = 0; ch < 4; ++ch) x[ch] = *(const float4*)(src + ch * 64 + lm * 4);
    float sum = 0.f, ssq = 0.f;
    #pragma unroll
    for (int ch = 0; ch < 4; ++ch) {
      sum += x[ch].x + x[ch].y + x[ch].z + x[ch].w;
      ssq += x[ch].x * x[ch].x + x[ch].y * x[ch].y + x[ch].z * x[ch].z + x[ch].w * x[ch].w;
    }
    #pragma unroll
    for (int m = 1; m < 16; m <<= 1) {
      sum += __shfl_xor(sum, m);
      ssq += __shfl_xor(ssq, m);
    }
    float mu = sum * (1.0f / CM);
    float var = ssq * (1.0f / CM) - mu * mu;
    float rs = rsqrtf(var + 1e-5f);
    if (lm == 0) {
      smu[row] = mu; srs[row] = rs;
      smk[row] = mask[(size_t)sg * R_DIM + i];
    }
    #pragma unroll
    for (int ch = 0; ch < 4; ++ch) {
      ushort4 xb;
      xb.x = f2bf(x[ch].x); xb.y = f2bf(x[ch].y); xb.z = f2bf(x[ch].z); xb.w = f2bf(x[ch].w);
      *(ushort4*)(&xt[row * XPAD + ch * 64 + lm * 4]) = xb;
    }
  }
  __syncthreads();

  f32x4 acc[4] = {{0.f, 0.f, 0.f, 0.f}, {0.f, 0.f, 0.f, 0.f},
                  {0.f, 0.f, 0.f, 0.f}, {0.f, 0.f, 0.f, 0.f}};
  #pragma unroll
  for (int k = 0; k < 8; ++k) {
    const int c0 = k * 32 + ((lane >> 4) << 3);
    bf16x8 a = *(const bf16x8*)(&wp[(w * 16 + (lane & 15)) * XPAD + c0]);
    #pragma unroll
    for (int nt = 0; nt < 4; ++nt) {
      bf16x8 b = *(const bf16x8*)(&xt[(nt * 16 + (lane & 15)) * XPAD + c0]);
      acc[nt] = __builtin_amdgcn_mfma_f32_16x16x32_bf16(a, b, acc[nt], 0, 0, 0);
    }
  }

  // epilogue: v -> LDS transpose buffer ot[o][s]
  #pragma unroll
  for (int nt = 0; nt < 4; ++nt) {
    int srow = nt * 16 + (lane & 15);
    float mu = smu[srow], rs = srs[srow], mk = smk[srow];
    #pragma unroll
    for (int r = 0; r < 4; ++r) {
      int o = w * 16 + ((lane >> 4) << 2) + r;
      float v = (rs * (acc[nt][r] - mu * sKa[o]) + sCa[o]) * mk;
      ot[o * OTP + srow] = f2bf(v);
    }
  }
  __syncthreads();

  // coalesced b128 stores: thread -> (o, s-group)
  #pragma unroll
  for (int rep = 0; rep < 2; ++rep) {
    int idx = rep * 256 + t;
    int o = idx >> 3, sg = idx & 7;
    ushort4 lo = *(const ushort4*)(&ot[o * OTP + sg * 8]);
    ushort4 hi = *(const ushort4*)(&ot[o * OTP + sg * 8 + 4]);
    size_t dst = (size_t)(blockIdx.y * 8 + sg) * 65536;
    uint4 v; v.x = (u32)lo.x | ((u32)lo.y << 16); v.y = (u32)lo.z | ((u32)lo.w << 16);
    v.z = (u32)hi.x | ((u32)hi.y << 16); v.w = (u32)hi.z | ((u32)hi.w << 16);
    if (o < 32) *(uint4*)(leftT + dst + (size_t)(i * 32 + o) * 8) = v;
    else        *(uint4*)(rightT + dst + (size_t)(i * 32 + (o - 32)) * 8) = v;
  }
}

// ---------------- K2: 256x256 tile, k-blocked global + k-major LDS, 16x16x32 MFMA ----------------
// r4 structure: full-unroll kt loop, 2 barriers/K-tile, counted vmcnt(8), dbuf 128KB,
// prefetch distance 2. Conflict-free k-major LDS. Fused Wo epilogue (k-major Wo stream).
#define NT2 8   // 512 / 64 K-tiles

__global__ __launch_bounds__(512, 1) void
opm_gemm_kernel(const unsigned short* __restrict__ leftT, const unsigned short* __restrict__ rightT,
                const unsigned short* __restrict__ Wo_bf, const float* __restrict__ bo,
                const float* __restrict__ scale, float* __restrict__ out) {
  extern __shared__ unsigned short smem[];  // 65536 shorts = 128 KiB

  const int t = threadIdx.x;
  const int lane = t & 63;
  const int lm = lane & 15, lq = lane >> 4;
  const int l31 = lane & 31, lq2 = lane >> 5;
  const int w = t >> 6;            // 0..7
  const int wm = w >> 2, wn = w & 3;

  // XCD chunk = 128 blocks; within chunk bx-major: A panels L2-resident
  const int bid = blockIdx.x;
  const int xcd = bid & 7, local = bid >> 3;
  const int by = xcd * 4 + (local & 3);
  const int bx = local >> 2;

  const unsigned short* Asrc = leftT + (size_t)(by * 256) * 8;
  const unsigned short* Bsrc = rightT + (size_t)(bx * 256) * 8;

  // staging: chunk c -> plane c>>8 (0..7), row c&255; LDS dest c*8; all linear
  int goff[4], ldso[4];
  #pragma unroll
  for (int q = 0; q < 4; ++q) {
    int c = q * 512 + t;
    goff[q] = (c >> 8) * 65536 + (c & 255) * 8;
    ldso[q] = c * 8;
  }

  f32x4 acc[8][4];
  #pragma unroll
  for (int a = 0; a < 8; ++a)
    #pragma unroll
    for (int b = 0; b < 4; ++b) acc[a][b] = (f32x4){0.f, 0.f, 0.f, 0.f};

  // STAGE: 8 gloads/thread (4 A + 4 B)
  auto STAGE = [&](int kt, int buf) {
    const size_t kb = (size_t)kt * 8 * 65536;
    unsigned short* ab = smem + buf * 32768;
    #pragma unroll
    for (int q = 0; q < 4; ++q) {
      gload_lds16(Asrc + kb + goff[q], ab + ldso[q]);
      gload_lds16(Bsrc + kb + goff[q], ab + 16384 + ldso[q]);
    }
  };

  STAGE(0, 0);
  STAGE(1, 1);

  // per-wave fragment bases (shorts): plane stride 2048, A rows wm*128.., B rows wn*64..
  const int abase = lq * 2048 + (wm * 128 + lm) * 8;
  const int bbase = 16384 + lq * 2048 + (wn * 64 + lm) * 8;

  #pragma unroll
  for (int kt = 0; kt < NT2; ++kt) {
    if (kt < NT2 - 1) asm volatile("s_waitcnt vmcnt(8)" ::: "memory");
    else              asm volatile("s_waitcnt vmcnt(0)" ::: "memory");
    wave_bar();

    const unsigned short* Ab = smem + (kt & 1) * 32768;
    #pragma unroll
    for (int ks = 0; ks < 2; ++ks) {
      bf16x8 af[8], bfr[4];
      #pragma unroll
      for (int mi = 0; mi < 8; ++mi)
        af[mi] = *(const bf16x8*)(&Ab[abase + ks * 8192 + mi * 128]);
      #pragma unroll
      for (int ni = 0; ni < 4; ++ni)
        bfr[ni] = *(const bf16x8*)(&Ab[bbase + ks * 8192 + ni * 128]);
      #pragma unroll
      for (int mi = 0; mi < 8; ++mi)
        #pragma unroll
        for (int ni = 0; ni < 4; ++ni)
          acc[mi][ni] = __builtin_amdgcn_mfma_f32_16x16x32_bf16(af[mi], bfr[ni], acc[mi][ni], 0, 0, 0);
    }

    wave_bar();
    if (kt + 2 < NT2) STAGE(kt + 2, kt & 1);
  }

  // ---- epilogue part 1: acc -> O [kg = k'>>3][entry = pair ^ (kg>>2) ^ (kg&3)] 16B,
  //      k' = e*32+d (matches k-major Wo); b64 writes ----
  #pragma unroll
  for (int mi = 0; mi < 8; ++mi) {
    const int m0 = wm * 128 + mi * 16 + lq * 4;
    const int il = m0 >> 5, d0 = m0 & 31;
    #pragma unroll
    for (int ni = 0; ni < 4; ++ni) {
      const int n = wn * 64 + ni * 16 + lm;
      const int jl = n >> 5, e = n & 31;
      const int pair = il * 8 + jl;
      const int kg = e * 4 + (d0 >> 3);
      const u32 byte = (u32)kg * 1024 + (u32)((pair ^ (kg >> 2) ^ (kg & 3)) * 16 + (d0 & 4) * 2);
      ushort4 v4;
      v4.x = f2bf(acc[mi][ni][0]); v4.y = f2bf(acc[mi][ni][1]);
      v4.z = f2bf(acc[mi][ni][2]); v4.w = f2bf(acc[mi][ni][3]);
      *(ushort4*)((char*)smem + byte) = v4;
    }
  }
  __syncthreads();

  // ---- epilogue part 2: Z[pair][z] = O . Wo  (wave: 32 pairs (wm) x 32 z (wn), K=1024) ----
  f32x16 zacc;
  #pragma unroll
  for (int r = 0; r < 16; ++r) zacc[r] = 0.f;
  // k-major Wo: plane kg (1024 shorts = 128 z x 8), lane reads z-row contiguous
  const unsigned short* wop = Wo_bf + lq2 * 1024 + (size_t)(wn * 32 + l31) * 8;
  #pragma unroll 4
  for (int kk = 0; kk < 64; ++kk) {
    bf16x8 bw = *(const bf16x8*)(wop + kk * 2048);
    const int kg = kk * 2 + lq2;
    const u32 ob = (u32)kg * 1024 + (u32)((((wm * 32 + l31) ^ (kg >> 2) ^ (kg & 3))) * 16);
    bf16x8 oa = *(const bf16x8*)((const char*)smem + ob);
    zacc = __builtin_amdgcn_mfma_f32_32x32x16_bf16(oa, bw, zacc, 0, 0, 0);
  }

  const int z = wn * 32 + l31;
  const float bz = bo[z];
  #pragma unroll
  for (int r = 0; r < 16; ++r) {
    const int pair = wm * 32 + (r & 3) + 8 * (r >> 2) + 4 * lq2;
    const int ig = by * 8 + (pair >> 3), jg = bx * 8 + (pair & 7);
    float v = (zacc[r] + bz) * scale[ig * R_DIM + jg];
    out[((size_t)ig * R_DIM + jg) * CZ + z] = v;
  }
}

extern "C" void kernel_launch(void* const* d_in, const int* in_sizes, int n_in,
                              void* d_out, int out_size, void* d_ws, size_t ws_size,
                              hipStream_t stream) {
  const float* M     = (const float*)d_in[0];
  const float* Mmask = (const float*)d_in[1];
  const float* ln_g  = (const float*)d_in[3];
  const float* ln_b  = (const float*)d_in[4];
  const float* Wa    = (const float*)d_in[5];
  const float* ba    = (const float*)d_in[6];
  const float* Wb    = (const float*)d_in[7];
  const float* bb    = (const float*)d_in[8];
  const float* Wo    = (const float*)d_in[9];
  const float* bo    = (const float*)d_in[10];
  float* out = (float*)d_out;

  char* ws = (char*)d_ws;
  unsigned short* leftT  = (unsigned short*)(ws);
  unsigned short* rightT = (unsigned short*)(ws + 8388608);
  unsigned short* wp     = (unsigned short*)(ws + 16777216);
  float*          Ka     = (float*)(ws + 16810240);
  float*          Ca     = (float*)(ws + 16810496);
  unsigned short* Wo_bf  = (unsigned short*)(ws + 16810752);
  float*          scale  = (float*)(ws + 17072896);
  (void)ws_size; (void)in_sizes; (void)n_in; (void)out_size;

  hipFuncSetAttribute((const void*)opm_gemm_kernel,
                      hipFuncAttributeMaxDynamicSharedMemorySize, 131072);

  hipLaunchKernelGGL(fused_prep_kernel, dim3(832), dim3(256), 0, stream,
                     Wa, ba, Wb, bb, ln_g, ln_b, Wo, Mmask, wp, Ka, Ca, Wo_bf, scale);
  hipLaunchKernelGGL(ln_proj_kernel, dim3(R_DIM, S_DIM / K1_ROWS), dim3(256), 0, stream,
                     M, Mmask, wp, Ka, Ca, leftT, rightT);
  hipLaunchKernelGGL(opm_gemm_kernel, dim3(1024), dim3(512), 131072, stream,
                     leftT, rightT, Wo_bf, bo, scale, out);
}